// Round 10
// baseline (189.008 us; speedup 1.0000x reference)
//
#include <hip/hip_runtime.h>
#include <hip/hip_bf16.h>
#include <hip/hip_cooperative_groups.h>

namespace cgx = cooperative_groups;

// Problem constants (fixed by the reference)
#define Bz 8
#define Cc 256
#define HWp 23104            // 152*152
#define Kk 1024
#define BK (Bz*Kk)
#define MARGIN_F 10.0f
#define BIGF 1e30f
#define TILE 128
#define NWORK 512            // work units per stage (gather: 64 cg x 8 b; gram: 64 tiles x 8 b)

typedef __attribute__((ext_vector_type(8))) short bf16x8;  // 8 bf16 = 4 VGPRs
typedef __attribute__((ext_vector_type(4))) float f32x4;   // MFMA 16x16 accumulator

__device__ __forceinline__ uint pk2(float a, float b) {
    return (uint)__hip_bfloat16_raw(__float2bfloat16(a)).x
         | ((uint)__hip_bfloat16_raw(__float2bfloat16(b)).x << 16);
}

// ---------------------------------------------------------------------------
// Stage bodies shared by the cooperative kernel AND the 4-kernel fallback
// (bitwise-identical math to the verified R5/R6/R7 kernels).
// ---------------------------------------------------------------------------

// stage 1: direct scattered gather (R7 body) + neg_min init
__device__ __forceinline__ void stage_gather(int g, int tid,
    const float* __restrict__ x, const int* __restrict__ ind,
    __hip_bfloat16* __restrict__ embr, unsigned* __restrict__ neg)
{
    const int cgi = g & 63, b = g >> 6;
    const int c0  = cgi * 4;
    const int*   indb = ind + b * Kk;
    const float* xb   = x + (size_t)b * Cc * HWp;
    #pragma unroll
    for (int q = 0; q < 4; ++q) {
        int k  = q * 256 + tid;
        int hw = indb[k];
        float v0 = xb[(size_t)(c0 + 0) * HWp + hw];
        float v1 = xb[(size_t)(c0 + 1) * HWp + hw];
        float v2 = xb[(size_t)(c0 + 2) * HWp + hw];
        float v3 = xb[(size_t)(c0 + 3) * HWp + hw];
        uint2 o;
        o.x = pk2(v0, v1);
        o.y = pk2(v2, v3);
        *(uint2*)((ushort*)embr + (size_t)(b * Kk + k) * Cc + c0) = o;
    }
    if (cgi == 0) {
        #pragma unroll
        for (int q = 0; q < 4; ++q)
            neg[b * Kk + q * 256 + tid] = __float_as_uint(BIGF);
    }
}

// stage 2: rownorm (R6 body; 16 rows per work unit)
__device__ __forceinline__ void stage_rownorm(int g, int tid,
    const __hip_bfloat16* __restrict__ embr, float* __restrict__ scl)
{
    const int w = tid >> 6, lane = tid & 63;
    #pragma unroll
    for (int r = 0; r < 4; ++r) {
        int row = g * 16 + r * 4 + w;
        uint2 v = *((const uint2*)((const ushort*)embr + (size_t)row * Cc) + lane);
        float f0 = __uint_as_float(v.x << 16);
        float f1 = __uint_as_float(v.x & 0xffff0000u);
        float f2 = __uint_as_float(v.y << 16);
        float f3 = __uint_as_float(v.y & 0xffff0000u);
        float s = f0*f0 + f1*f1 + f2*f2 + f3*f3;
        #pragma unroll
        for (int off = 32; off; off >>= 1) s += __shfl_xor(s, off);
        if (lane == 0)
            scl[row] = 10.0f / fmaxf(sqrtf(s), 1e-12f);
    }
}

// stage 3: MFMA gram + fused masked-min (R5 body).
// d2 = 200 - 2*scl_i*scl_j*Graw (||emb||^2 == 100 by construction), clamped
// >= 0 BEFORE the uint-bit atomicMin (duplicate-index pairs = the signal).
__device__ __forceinline__ void stage_gram(int g, int tid,
    short* As, short* Bs,
    const __hip_bfloat16* __restrict__ embr, const float* __restrict__ scl,
    const int* __restrict__ mask, unsigned* __restrict__ neg)
{
    const int b = g >> 6, tile = g & 63;
    const int i0 = (tile >> 3) * TILE, j0 = (tile & 7) * TILE;
    const int w = tid >> 6, lane = tid & 63;
    const int wr = w >> 1, wc = w & 1;          // wave's 64x64 quadrant
    const int lr = lane & 15, lg = lane >> 4;

    const short* E  = (const short*)embr + (size_t)b * Kk * Cc;
    const short* EA = E + (size_t)i0 * Cc;
    const short* EB = E + (size_t)j0 * Cc;

    // staging: instr t (=w*4+q) fills LDS rows t*8..t*8+7; lane l ->
    // row offset l/8, slot l%8; source k-chunk = (l%8) ^ (l/8).
    const int lrow = lane >> 3;
    const int lsub = (lane & 7) ^ lrow;

    f32x4 acc[4][4] = {};
    for (int k0 = 0; k0 < Cc; k0 += 64) {
        #pragma unroll
        for (int q = 0; q < 4; ++q) {
            int t = w * 4 + q;
            int r = t * 8 + lrow;
            __builtin_amdgcn_global_load_lds(
                (const __attribute__((address_space(1))) void*)(EA + (size_t)r * Cc + k0 + lsub * 8),
                (__attribute__((address_space(3))) void*)&As[t * 512], 16, 0, 0);
            __builtin_amdgcn_global_load_lds(
                (const __attribute__((address_space(1))) void*)(EB + (size_t)r * Cc + k0 + lsub * 8),
                (__attribute__((address_space(3))) void*)&Bs[t * 512], 16, 0, 0);
        }
        __syncthreads();

        #pragma unroll
        for (int kk = 0; kk < 2; ++kk) {
            bf16x8 af[4], bf[4];
            #pragma unroll
            for (int f = 0; f < 4; ++f) {
                int ra = wr * 64 + f * 16 + lr;
                af[f] = *(const bf16x8*)&As[ra * 64 + (((kk * 4 + lg) ^ (ra & 7)) << 3)];
                int rb = wc * 64 + f * 16 + lr;
                bf[f] = *(const bf16x8*)&Bs[rb * 64 + (((kk * 4 + lg) ^ (rb & 7)) << 3)];
            }
            #pragma unroll
            for (int fi = 0; fi < 4; ++fi)
                #pragma unroll
                for (int fj = 0; fj < 4; ++fj)
                    acc[fi][fj] = __builtin_amdgcn_mfma_f32_16x16x32_bf16(
                                      af[fi], bf[fj], acc[fi][fj], 0, 0, 0);
        }
        __syncthreads();
    }

    const int* mb = mask + b * Kk;
    float cjv[4]; int jgv[4]; bool jva[4];
    #pragma unroll
    for (int fj = 0; fj < 4; ++fj) {
        int jg = j0 + wc*64 + fj*16 + lr;
        jgv[fj] = jg;
        cjv[fj] = scl[b * Kk + jg];
        jva[fj] = (mb[jg] != 0);
    }
    #pragma unroll
    for (int fi = 0; fi < 4; ++fi) {
        #pragma unroll
        for (int r = 0; r < 4; ++r) {
            int ig = i0 + wr*64 + fi*16 + 4*lg + r;
            float ci = scl[b * Kk + ig];
            float m = BIGF;
            #pragma unroll
            for (int fj = 0; fj < 4; ++fj) {
                float d2 = fmaxf(200.0f - 2.0f * ci * cjv[fj] * acc[fi][fj][r], 0.0f);
                bool ok = jva[fj] && (jgv[fj] != ig);
                m = ok ? fminf(m, d2) : m;
            }
            #pragma unroll
            for (int off = 1; off < 16; off <<= 1)
                m = fminf(m, __shfl_xor(m, off));
            if (lr == 0)
                atomicMin(&neg[b * Kk + ig], __float_as_uint(m));
        }
    }
}

// stage 4: hinge + mean, one 256-thread block; shf = 8-float LDS scratch
__device__ __forceinline__ void stage_hinge(int tid, float* shf,
    const unsigned* __restrict__ neg, const int* __restrict__ mask,
    float* __restrict__ out)
{
    const int w = tid >> 6, lane = tid & 63;
    float h = 0.f, v = 0.f;
    for (int i = tid; i < BK; i += 256) {
        if (mask[i] != 0) {
            float d = sqrtf(__uint_as_float(neg[i]));
            h += fmaxf(MARGIN_F - d, 0.f);
            v += 1.f;
        }
    }
    #pragma unroll
    for (int off = 32; off; off >>= 1) {
        h += __shfl_xor(h, off);
        v += __shfl_xor(v, off);
    }
    if (lane == 0) { shf[w] = h; shf[4 + w] = v; }
    __syncthreads();
    if (tid == 0)
        out[0] = (shf[0] + shf[1] + shf[2] + shf[3])
               / (shf[4] + shf[5] + shf[6] + shf[7]);
}

// ---------------------------------------------------------------------------
// Cooperative fused kernel.  LDS = exactly 32768 B (stage-4 scratch ALIASED
// into As — R8's 32800 B likely tripped the runtime's coop-occupancy check).
// Grid-strides over NWORK units so ANY granted grid size <= 512 is correct.
// ---------------------------------------------------------------------------
__global__ __launch_bounds__(256) void fused_pairloss(
    const float* __restrict__ x, const int* __restrict__ ind,
    const int* __restrict__ mask, __hip_bfloat16* __restrict__ embr,
    float* __restrict__ scl, unsigned* __restrict__ neg,
    float* __restrict__ out)
{
    __shared__ __align__(16) short As[TILE * 64];   // 16 KB
    __shared__ __align__(16) short Bs[TILE * 64];   // 16 KB  (total exactly 32 KB)
    const int tid = threadIdx.x;

    for (int g = blockIdx.x; g < NWORK; g += gridDim.x)
        stage_gather(g, tid, x, ind, embr, neg);
    cgx::this_grid().sync();

    for (int g = blockIdx.x; g < NWORK; g += gridDim.x)
        stage_rownorm(g, tid, embr, scl);
    cgx::this_grid().sync();

    for (int g = blockIdx.x; g < NWORK; g += gridDim.x)
        stage_gram(g, tid, As, Bs, embr, scl, mask, neg);
    cgx::this_grid().sync();

    if (blockIdx.x == 0)
        stage_hinge(tid, (float*)As, neg, mask, out);
}

// ---------------------------------------------------------------------------
// Fallback wrappers (= exact R7 pipeline; bitwise-identical results).
// ---------------------------------------------------------------------------
__global__ __launch_bounds__(256) void k_gather(
    const float* __restrict__ x, const int* __restrict__ ind,
    __hip_bfloat16* __restrict__ embr, unsigned* __restrict__ neg)
{
    stage_gather(blockIdx.x, threadIdx.x, x, ind, embr, neg);
}

__global__ __launch_bounds__(256) void k_rownorm(
    const __hip_bfloat16* __restrict__ embr, float* __restrict__ scl)
{
    stage_rownorm(blockIdx.x, threadIdx.x, embr, scl);
}

__global__ __launch_bounds__(256) void k_gram(
    const __hip_bfloat16* __restrict__ embr, const float* __restrict__ scl,
    const int* __restrict__ mask, unsigned* __restrict__ neg)
{
    __shared__ __align__(16) short As[TILE * 64];
    __shared__ __align__(16) short Bs[TILE * 64];
    stage_gram(blockIdx.x, threadIdx.x, As, Bs, embr, scl, mask, neg);
}

__global__ __launch_bounds__(256) void k_hinge(
    const unsigned* __restrict__ neg, const int* __restrict__ mask,
    float* __restrict__ out)
{
    __shared__ float shf[8];
    stage_hinge(threadIdx.x, shf, neg, mask, out);
}

// ---------------------------------------------------------------------------
extern "C" void kernel_launch(void* const* d_in, const int* in_sizes, int n_in,
                              void* d_out, int out_size, void* d_ws, size_t ws_size,
                              hipStream_t stream) {
    const float* x    = (const float*)d_in[0];   // [B,C,H,W] fp32
    const int*   ind  = (const int*)d_in[1];     // [B,K] int32
    const int*   mask = (const int*)d_in[2];     // [B,K] int32
    float* out = (float*)d_out;

    // ws layout: embr bf16 [B*K][C] (4 MB) | scl f32 [B*K] | neg u32 [B*K]
    __hip_bfloat16* embr = (__hip_bfloat16*)d_ws;
    float*    scl = (float*)((char*)d_ws + (size_t)BK * Cc * sizeof(__hip_bfloat16));
    unsigned* neg = (unsigned*)(scl + BK);

    // Size the cooperative grid from the runtime's own occupancy answer so
    // the TooLarge check can never fire; grid-stride keeps any size correct.
    bool coop_ok = false;
    int perCU = 0;
    hipError_t qerr = hipOccupancyMaxActiveBlocksPerMultiprocessor(
        &perCU, fused_pairloss, 256, 0);
    if (qerr == hipSuccess && perCU > 0) {
        int nb = perCU * 256;                 // 256 CUs on MI355X
        if (nb > NWORK) nb = NWORK;
        void* args[] = {(void*)&x, (void*)&ind, (void*)&mask,
                        (void*)&embr, (void*)&scl, (void*)&neg, (void*)&out};
        hipError_t lerr = hipLaunchCooperativeKernel(
            (const void*)fused_pairloss, dim3(nb), dim3(256), args, 0, stream);
        coop_ok = (lerr == hipSuccess);
    }

    if (!coop_ok) {
        // Proven R7 4-kernel pipeline (bitwise-identical results).
        dim3 g0(NWORK);
        k_gather <<<g0, 256, 0, stream>>>(x, ind, embr, neg);
        k_rownorm<<<NWORK, 256, 0, stream>>>(embr, scl);
        k_gram   <<<NWORK, 256, 0, stream>>>(embr, scl, mask, neg);
        k_hinge  <<<1, 256, 0, stream>>>(neg, mask, out);
    }
}

// Round 11
// 89.511 us; speedup vs baseline: 2.1116x; 2.1116x over previous
//
#include <hip/hip_runtime.h>
#include <hip/hip_bf16.h>

// Problem constants (fixed by the reference)
#define Bz 8
#define Cc 256
#define HWp 23104            // 152*152 = 76 slices * 304
#define SLC 304              // floats per slice (1216 B, 64B-aligned starts)
#define NSL 76
#define Kk 1024
#define BK (Bz*Kk)
#define MARGIN_F 10.0f
#define BIGF 1e30f
#define TILE 128

typedef __attribute__((ext_vector_type(8))) short bf16x8;  // 8 bf16 = 4 VGPRs
typedef __attribute__((ext_vector_type(4))) float f32x4;   // MFMA 16x16 accumulator

// ---------------------------------------------------------------------------
// K1: DMA stream-gather (verified R6 body) + fused per-cg ssq partials +
// neg/cnt init.  Block = (slice, 32-channel group, batch) = 76x8x8 = 4864.
//   reads : global_load_lds width=16, fp32 slice rows into LDS (189 MB total,
//           linear both sides per rule #21), deep vmcnt queue
//   gather: ~13.5 in-range k per block; convert bf16, pack, ssq over the 32
//           ROUNDED values (keeps duplicate rows bitwise-identical + scl eq)
//   writes: ONE 64B line embr[k][c0..c0+31] per hit (exactly once) +
//           ssq_part[cg][b*K+k] (exactly once -- k maps to exactly 1 slice)
// ---------------------------------------------------------------------------
__global__ __launch_bounds__(256) void stream_gather(
    const float* __restrict__ x, const int* __restrict__ ind,
    __hip_bfloat16* __restrict__ embr, float* __restrict__ ssq_part,
    unsigned* __restrict__ neg, unsigned* __restrict__ cnt)
{
    __shared__ float pl[32 * SLC];                 // 38912 B -> 4 blocks/CU
    int s  = blockIdx.x;                           // slice 0..75
    int cg = blockIdx.y;                           // channel group 0..7
    int b  = blockIdx.z;
    int c0 = cg * 32;
    int tid = threadIdx.x, lane = tid & 63, w = tid >> 6;
    int lo = s * SLC;

    #pragma unroll
    for (int rr = 0; rr < 8; ++rr) {
        int row = w * 8 + rr;
        const float* src = x + (size_t)(b * Cc + c0 + row) * HWp + lo;
        __builtin_amdgcn_global_load_lds(
            (const __attribute__((address_space(1))) void*)(src + lane * 4),
            (__attribute__((address_space(3))) void*)&pl[row * SLC], 16, 0, 0);
        if (lane < 12)
            __builtin_amdgcn_global_load_lds(
                (const __attribute__((address_space(1))) void*)(src + 256 + lane * 4),
                (__attribute__((address_space(3))) void*)&pl[row * SLC + 256], 16, 0, 0);
    }
    // init work overlapped with the in-flight loads (ws poisoned once only)
    if (s == 0 && cg == 0) {
        #pragma unroll
        for (int q = 0; q < 4; ++q)
            neg[b * Kk + q * 256 + tid] = __float_as_uint(BIGF);
        if (b == 0 && tid == 0) *cnt = 0u;
    }
    __syncthreads();   // compiler drains vmcnt before s_barrier

    const int* indb = ind + b * Kk;
    #pragma unroll
    for (int q = 0; q < 4; ++q) {
        int k = q * 256 + tid;
        unsigned off = (unsigned)(indb[k] - lo);
        if (off < (unsigned)SLC) {
            uint dw[16]; float s2 = 0.f;
            #pragma unroll
            for (int c2 = 0; c2 < 16; ++c2) {
                float fa = pl[(2 * c2 + 0) * SLC + off];
                float fb = pl[(2 * c2 + 1) * SLC + off];
                ushort ea = __hip_bfloat16_raw(__float2bfloat16(fa)).x;
                ushort eb = __hip_bfloat16_raw(__float2bfloat16(fb)).x;
                float va = __uint_as_float((uint)ea << 16);
                float vb = __uint_as_float((uint)eb << 16);
                s2 += va * va + vb * vb;
                dw[c2] = (uint)ea | ((uint)eb << 16);
            }
            ushort* dst = (ushort*)embr + (size_t)(b * Kk + k) * Cc + c0;
            ((uint4*)dst)[0] = make_uint4(dw[0],  dw[1],  dw[2],  dw[3]);
            ((uint4*)dst)[1] = make_uint4(dw[4],  dw[5],  dw[6],  dw[7]);
            ((uint4*)dst)[2] = make_uint4(dw[8],  dw[9],  dw[10], dw[11]);
            ((uint4*)dst)[3] = make_uint4(dw[12], dw[13], dw[14], dw[15]);
            ssq_part[cg * BK + b * Kk + k] = s2;
        }
    }
}

// ---------------------------------------------------------------------------
// K2: gram (verified R5 MFMA body) + absorbed rownorm (preamble sums the 8
// ssq partials per row -> scl in LDS) + absorbed hinge (last-block pattern:
// threadfence + atomicAdd(cnt); 512th block reads neg via device-scope
// atomic RMW -- safe across non-coherent XCD L2s -- and writes the scalar).
// d2 = 200 - 2*scl_i*scl_j*Graw (||emb||^2 == 100 by construction), clamped
// >= 0 BEFORE the uint-bit atomicMin (duplicate-index pairs = the signal).
// ---------------------------------------------------------------------------
__global__ __launch_bounds__(256) void gram_min_hinge(
    const __hip_bfloat16* __restrict__ emb, const float* __restrict__ ssq_part,
    const int* __restrict__ mask, unsigned* __restrict__ neg,
    unsigned* __restrict__ cnt, float* __restrict__ out)
{
    __shared__ __align__(16) short As[TILE * 64];   // 16 KB
    __shared__ __align__(16) short Bs[TILE * 64];   // 16 KB
    __shared__ float scl_i[TILE], scl_j[TILE];      // 1 KB
    __shared__ unsigned lastFlag;

    const int g = blockIdx.x;
    const int b = g >> 6, tile = g & 63;
    const int i0 = (tile >> 3) * TILE, j0 = (tile & 7) * TILE;
    const int tid = threadIdx.x, w = tid >> 6, lane = tid & 63;
    const int wr = w >> 1, wc = w & 1;          // wave's 64x64 quadrant
    const int lr = lane & 15, lg = lane >> 4;

    // ---- preamble: scl for this block's 128 i-rows and 128 j-rows --------
    {
        int rl  = tid & 127;
        int isj = tid >> 7;
        int grow = b * Kk + (isj ? j0 : i0) + rl;
        float ssum = 0.f;
        #pragma unroll
        for (int c = 0; c < 8; ++c) ssum += ssq_part[c * BK + grow];
        float sc = 10.0f / fmaxf(sqrtf(ssum), 1e-12f);
        if (isj) scl_j[rl] = sc; else scl_i[rl] = sc;
    }
    __syncthreads();

    const short* E  = (const short*)emb + (size_t)b * Kk * Cc;
    const short* EA = E + (size_t)i0 * Cc;
    const short* EB = E + (size_t)j0 * Cc;

    // staging: instr t (=w*4+q) fills LDS rows t*8..t*8+7; lane l ->
    // row offset l/8, slot l%8; source k-chunk = (l%8) ^ (l/8).
    const int lrow = lane >> 3;
    const int lsub = (lane & 7) ^ lrow;

    f32x4 acc[4][4] = {};
    for (int k0 = 0; k0 < Cc; k0 += 64) {
        #pragma unroll
        for (int q = 0; q < 4; ++q) {
            int t = w * 4 + q;
            int r = t * 8 + lrow;
            __builtin_amdgcn_global_load_lds(
                (const __attribute__((address_space(1))) void*)(EA + (size_t)r * Cc + k0 + lsub * 8),
                (__attribute__((address_space(3))) void*)&As[t * 512], 16, 0, 0);
            __builtin_amdgcn_global_load_lds(
                (const __attribute__((address_space(1))) void*)(EB + (size_t)r * Cc + k0 + lsub * 8),
                (__attribute__((address_space(3))) void*)&Bs[t * 512], 16, 0, 0);
        }
        __syncthreads();

        #pragma unroll
        for (int kk = 0; kk < 2; ++kk) {
            bf16x8 af[4], bf[4];
            #pragma unroll
            for (int f = 0; f < 4; ++f) {
                int ra = wr * 64 + f * 16 + lr;
                af[f] = *(const bf16x8*)&As[ra * 64 + (((kk * 4 + lg) ^ (ra & 7)) << 3)];
                int rb = wc * 64 + f * 16 + lr;
                bf[f] = *(const bf16x8*)&Bs[rb * 64 + (((kk * 4 + lg) ^ (rb & 7)) << 3)];
            }
            #pragma unroll
            for (int fi = 0; fi < 4; ++fi)
                #pragma unroll
                for (int fj = 0; fj < 4; ++fj)
                    acc[fi][fj] = __builtin_amdgcn_mfma_f32_16x16x32_bf16(
                                      af[fi], bf[fj], acc[fi][fj], 0, 0, 0);
        }
        __syncthreads();
    }

    const int* mb = mask + b * Kk;
    float cjv[4]; int jgv[4]; bool jva[4];
    #pragma unroll
    for (int fj = 0; fj < 4; ++fj) {
        int jl = wc * 64 + fj * 16 + lr;
        jgv[fj] = j0 + jl;
        cjv[fj] = scl_j[jl];
        jva[fj] = (mb[j0 + jl] != 0);
    }
    #pragma unroll
    for (int fi = 0; fi < 4; ++fi) {
        #pragma unroll
        for (int r = 0; r < 4; ++r) {
            int il = wr * 64 + fi * 16 + 4 * lg + r;
            int ig = i0 + il;
            float ci = scl_i[il];
            float m = BIGF;
            #pragma unroll
            for (int fj = 0; fj < 4; ++fj) {
                float d2 = fmaxf(200.0f - 2.0f * ci * cjv[fj] * acc[fi][fj][r], 0.0f);
                bool ok = jva[fj] && (jgv[fj] != ig);
                m = ok ? fminf(m, d2) : m;
            }
            #pragma unroll
            for (int off = 1; off < 16; off <<= 1)
                m = fminf(m, __shfl_xor(m, off));
            if (lr == 0)
                atomicMin(&neg[b * Kk + ig], __float_as_uint(m));
        }
    }

    // ---- last-block hinge + mean ------------------------------------------
    __threadfence();                               // publish our atomicMins
    if (tid == 0)
        lastFlag = (atomicAdd(cnt, 1u) == (unsigned)(gridDim.x - 1)) ? 1u : 0u;
    __syncthreads();
    if (lastFlag) {
        float h = 0.f, v = 0.f;
        for (int i = tid; i < BK; i += 256) {
            unsigned nb = atomicAdd(&neg[i], 0u);  // device-scope coherent read
            if (mask[i] != 0) {
                float d = sqrtf(__uint_as_float(nb));
                h += fmaxf(MARGIN_F - d, 0.f);
                v += 1.f;
            }
        }
        #pragma unroll
        for (int off = 32; off; off >>= 1) {
            h += __shfl_xor(h, off);
            v += __shfl_xor(v, off);
        }
        if (lane == 0) { scl_i[w] = h; scl_i[4 + w] = v; }
        __syncthreads();
        if (tid == 0)
            out[0] = (scl_i[0] + scl_i[1] + scl_i[2] + scl_i[3])
                   / (scl_i[4] + scl_i[5] + scl_i[6] + scl_i[7]);
    }
}

// ---------------------------------------------------------------------------
extern "C" void kernel_launch(void* const* d_in, const int* in_sizes, int n_in,
                              void* d_out, int out_size, void* d_ws, size_t ws_size,
                              hipStream_t stream) {
    const float* x    = (const float*)d_in[0];   // [B,C,H,W] fp32
    const int*   ind  = (const int*)d_in[1];     // [B,K] int32
    const int*   mask = (const int*)d_in[2];     // [B,K] int32
    float* out = (float*)d_out;

    // ws layout: embr bf16 [B*K][C] (4 MB) | ssq_part f32 [8][B*K] (256 KB)
    //            | neg u32 [B*K] (32 KB) | cnt u32
    __hip_bfloat16* embr = (__hip_bfloat16*)d_ws;
    float*    ssq_part = (float*)((char*)d_ws + (size_t)BK * Cc * sizeof(__hip_bfloat16));
    unsigned* neg = (unsigned*)(ssq_part + 8 * BK);
    unsigned* cnt = neg + BK;

    dim3 g1(NSL, Cc / 32, Bz);                // (76 slices, 8 cgroups, 8 b)
    stream_gather<<<g1, 256, 0, stream>>>(x, ind, embr, ssq_part, neg, cnt);
    gram_min_hinge<<<512, 256, 0, stream>>>(embr, ssq_part, mask, neg, cnt, out);
}

// Round 12
// 63.906 us; speedup vs baseline: 2.9576x; 1.4007x over previous
//
#include <hip/hip_runtime.h>
#include <hip/hip_bf16.h>

// Problem constants (fixed by the reference)
#define Bz 8
#define Cc 256
#define HWp 23104            // 152*152 = 152 slices * 152
#define SLC 152              // floats per slice (608 B; starts 16B-aligned)
#define NSL 152
#define Kk 1024
#define BK (Bz*Kk)
#define MARGIN_F 10.0f
#define BIGF 1e30f
#define TILE 128

typedef __attribute__((ext_vector_type(8))) short bf16x8;  // 8 bf16 = 4 VGPRs
typedef __attribute__((ext_vector_type(4))) float f32x4;   // MFMA 16x16 accumulator

__device__ __forceinline__ uint pk2(float a, float b) {
    return (uint)__hip_bfloat16_raw(__float2bfloat16(a)).x
         | ((uint)__hip_bfloat16_raw(__float2bfloat16(b)).x << 16);
}

// ---------------------------------------------------------------------------
// K1: DMA stream-gather, now 8 blocks/CU (was 4).  R6..R10 ledger puts the
// gather at ~43-46us = only ~4.1 TB/s for a 189MB stream; theory: with 4
// resident blocks the single vmcnt-drain barrier per block periodically
// idles the CU (all 4 waves of a block stall together).  Halving LDS to
// 19456B doubles resident blocks -> barrier phases stagger across 8 blocks.
//   block = (slice, 32-channel group, batch) = 152x8x8 = 9728 blocks
//   reads : one global_load_lds width=16 per row, lanes<38 (608B, 16B-aligned
//           start; both sides linear per rule #21); +5% line overfetch
//   writes: UNCHANGED from the verified R6 pattern -- ONE full 64B line
//           embr[k][c0..c0+31] per hit, written exactly once
// ---------------------------------------------------------------------------
__global__ __launch_bounds__(256) void stream_gather(
    const float* __restrict__ x, const int* __restrict__ ind,
    __hip_bfloat16* __restrict__ embr, unsigned* __restrict__ neg)
{
    __shared__ float pl[32 * SLC];                 // 19456 B -> 8 blocks/CU
    int s  = blockIdx.x;                           // slice 0..151
    int c0 = blockIdx.y * 32;                      // channel group
    int b  = blockIdx.z;
    int tid = threadIdx.x, lane = tid & 63, w = tid >> 6;
    int lo = s * SLC;

    #pragma unroll
    for (int rr = 0; rr < 8; ++rr) {
        int row = w * 8 + rr;
        const float* src = x + (size_t)(b * Cc + c0 + row) * HWp + lo;
        if (lane < 38)                             // 38 lanes x 16B = 608 B
            __builtin_amdgcn_global_load_lds(
                (const __attribute__((address_space(1))) void*)(src + lane * 4),
                (__attribute__((address_space(3))) void*)&pl[row * SLC], 16, 0, 0);
    }
    // neg_min init overlapped with in-flight loads (ws poisoned once only)
    if (s == 0 && blockIdx.y == 0) {
        #pragma unroll
        for (int q = 0; q < 4; ++q)
            neg[b * Kk + q * 256 + tid] = __float_as_uint(BIGF);
    }
    __syncthreads();   // compiler drains vmcnt before s_barrier

    const int* indb = ind + b * Kk;
    #pragma unroll
    for (int q = 0; q < 4; ++q) {
        int k = q * 256 + tid;
        unsigned off = (unsigned)(indb[k] - lo);
        if (off < (unsigned)SLC) {
            uint dw[16];
            #pragma unroll
            for (int c2 = 0; c2 < 16; ++c2)
                dw[c2] = pk2(pl[(2 * c2 + 0) * SLC + off],
                             pl[(2 * c2 + 1) * SLC + off]);
            ushort* dst = (ushort*)embr + (size_t)(b * Kk + k) * Cc + c0;
            ((uint4*)dst)[0] = make_uint4(dw[0],  dw[1],  dw[2],  dw[3]);
            ((uint4*)dst)[1] = make_uint4(dw[4],  dw[5],  dw[6],  dw[7]);
            ((uint4*)dst)[2] = make_uint4(dw[8],  dw[9],  dw[10], dw[11]);
            ((uint4*)dst)[3] = make_uint4(dw[12], dw[13], dw[14], dw[15]);
        }
    }
}

// ---------------------------------------------------------------------------
// K2: rownorm — one wave per row (verbatim R6, proven).
// scl = 10/max(sqrt(ssq),eps) over the ROUNDED bf16 row (keeps duplicate
// rows bitwise-identical -> d2_dup ~ 0).
// ---------------------------------------------------------------------------
__global__ __launch_bounds__(256) void rownorm(
    const __hip_bfloat16* __restrict__ embr, float* __restrict__ scl)
{
    int row  = blockIdx.x * 4 + (threadIdx.x >> 6);
    int lane = threadIdx.x & 63;
    uint2 v = *((const uint2*)((const ushort*)embr + (size_t)row * Cc) + lane);
    float f0 = __uint_as_float(v.x << 16);
    float f1 = __uint_as_float(v.x & 0xffff0000u);
    float f2 = __uint_as_float(v.y << 16);
    float f3 = __uint_as_float(v.y & 0xffff0000u);
    float s = f0*f0 + f1*f1 + f2*f2 + f3*f3;
    #pragma unroll
    for (int off = 32; off; off >>= 1) s += __shfl_xor(s, off);
    if (lane == 0)
        scl[row] = 10.0f / fmaxf(sqrtf(s), 1e-12f);
}

// ---------------------------------------------------------------------------
// K3: Gram via bf16 MFMA with LDS-staged panels (verbatim R5/R6, proven) +
// fused masked-min.  d2 = 200 - 2*scl_i*scl_j*Graw (||emb||^2 == 100 by
// construction), clamped >= 0 BEFORE the uint-bit atomicMin.
// ---------------------------------------------------------------------------
__global__ __launch_bounds__(256) void gram_mfma_min(
    const __hip_bfloat16* __restrict__ emb, const float* __restrict__ scl,
    const int* __restrict__ mask, unsigned* __restrict__ neg)
{
    __shared__ __align__(16) short As[TILE * 64];   // 16 KB
    __shared__ __align__(16) short Bs[TILE * 64];   // 16 KB
    int b  = blockIdx.z;
    int i0 = blockIdx.y * TILE;
    int j0 = blockIdx.x * TILE;
    int w  = threadIdx.x >> 6, l = threadIdx.x & 63;
    int wr = w >> 1, wc = w & 1;          // wave's 64x64 quadrant
    int lr = l & 15, lg = l >> 4;         // lane row / k-group

    const short* E  = (const short*)emb + (size_t)b * Kk * Cc;
    const short* EA = E + (size_t)i0 * Cc;
    const short* EB = E + (size_t)j0 * Cc;

    // staging: instr t (=w*4+q) fills LDS rows t*8..t*8+7; lane l ->
    // row offset l/8, slot l%8; source k-chunk = (l%8) ^ (l/8).
    const int lrow = l >> 3;
    const int lsub = (l & 7) ^ lrow;

    f32x4 acc[4][4] = {};
    for (int k0 = 0; k0 < Cc; k0 += 64) {
        #pragma unroll
        for (int q = 0; q < 4; ++q) {
            int t = w * 4 + q;
            int r = t * 8 + lrow;
            __builtin_amdgcn_global_load_lds(
                (const __attribute__((address_space(1))) void*)(EA + (size_t)r * Cc + k0 + lsub * 8),
                (__attribute__((address_space(3))) void*)&As[t * 512], 16, 0, 0);
            __builtin_amdgcn_global_load_lds(
                (const __attribute__((address_space(1))) void*)(EB + (size_t)r * Cc + k0 + lsub * 8),
                (__attribute__((address_space(3))) void*)&Bs[t * 512], 16, 0, 0);
        }
        __syncthreads();

        #pragma unroll
        for (int kk = 0; kk < 2; ++kk) {
            bf16x8 af[4], bf[4];
            #pragma unroll
            for (int f = 0; f < 4; ++f) {
                int ra = wr * 64 + f * 16 + lr;
                af[f] = *(const bf16x8*)&As[ra * 64 + (((kk * 4 + lg) ^ (ra & 7)) << 3)];
                int rb = wc * 64 + f * 16 + lr;
                bf[f] = *(const bf16x8*)&Bs[rb * 64 + (((kk * 4 + lg) ^ (rb & 7)) << 3)];
            }
            #pragma unroll
            for (int fi = 0; fi < 4; ++fi)
                #pragma unroll
                for (int fj = 0; fj < 4; ++fj)
                    acc[fi][fj] = __builtin_amdgcn_mfma_f32_16x16x32_bf16(
                                      af[fi], bf[fj], acc[fi][fj], 0, 0, 0);
        }
        __syncthreads();
    }

    const int* mb = mask + b * Kk;
    float cjv[4]; int jgv[4]; bool jva[4];
    #pragma unroll
    for (int fj = 0; fj < 4; ++fj) {
        int jg = j0 + wc*64 + fj*16 + lr;
        jgv[fj] = jg;
        cjv[fj] = scl[b * Kk + jg];
        jva[fj] = (mb[jg] != 0);
    }
    #pragma unroll
    for (int fi = 0; fi < 4; ++fi) {
        #pragma unroll
        for (int r = 0; r < 4; ++r) {
            int ig = i0 + wr*64 + fi*16 + 4*lg + r;
            float ci = scl[b * Kk + ig];
            float m = BIGF;
            #pragma unroll
            for (int fj = 0; fj < 4; ++fj) {
                float d2 = fmaxf(200.0f - 2.0f * ci * cjv[fj] * acc[fi][fj][r], 0.0f);
                bool ok = jva[fj] && (jgv[fj] != ig);
                m = ok ? fminf(m, d2) : m;
            }
            #pragma unroll
            for (int off = 1; off < 16; off <<= 1)
                m = fminf(m, __shfl_xor(m, off));
            if (lr == 0)
                atomicMin(&neg[b * Kk + ig], __float_as_uint(m));
        }
    }
}

// ---------------------------------------------------------------------------
// K4: hinge + mean (verbatim R6, proven).
// ---------------------------------------------------------------------------
__global__ __launch_bounds__(1024) void hinge_final(
    const unsigned* __restrict__ neg, const int* __restrict__ mask,
    float* __restrict__ out)
{
    float h = 0.f, v = 0.f;
    for (int i = threadIdx.x; i < BK; i += 1024) {
        if (mask[i] != 0) {
            float d = sqrtf(__uint_as_float(neg[i]));
            h += fmaxf(MARGIN_F - d, 0.f);
            v += 1.f;
        }
    }
    #pragma unroll
    for (int off = 32; off; off >>= 1) {
        h += __shfl_xor(h, off);
        v += __shfl_xor(v, off);
    }
    __shared__ float sh[16], sv[16];
    int w = threadIdx.x >> 6;
    if ((threadIdx.x & 63) == 0) { sh[w] = h; sv[w] = v; }
    __syncthreads();
    if (threadIdx.x == 0) {
        float H = 0.f, V = 0.f;
        #pragma unroll
        for (int i = 0; i < 16; ++i) { H += sh[i]; V += sv[i]; }
        out[0] = H / V;
    }
}

// ---------------------------------------------------------------------------
extern "C" void kernel_launch(void* const* d_in, const int* in_sizes, int n_in,
                              void* d_out, int out_size, void* d_ws, size_t ws_size,
                              hipStream_t stream) {
    const float* x    = (const float*)d_in[0];   // [B,C,H,W] fp32
    const int*   ind  = (const int*)d_in[1];     // [B,K] int32
    const int*   mask = (const int*)d_in[2];     // [B,K] int32
    float* out = (float*)d_out;

    // ws layout: embr bf16 [B*K][C] (4 MB) | scl f32 [B*K] | neg u32 [B*K]
    __hip_bfloat16* embr = (__hip_bfloat16*)d_ws;
    float*    scl = (float*)((char*)d_ws + (size_t)BK * Cc * sizeof(__hip_bfloat16));
    unsigned* neg = (unsigned*)(scl + BK);

    dim3 g1(NSL, Cc / 32, Bz);                // (152 slices, 8 cgroups, 8 b)
    stream_gather<<<g1, 256, 0, stream>>>(x, ind, embr, neg);
    rownorm<<<BK / 4, 256, 0, stream>>>(embr, scl);
    dim3 g2(Kk / TILE, Kk / TILE, Bz);
    gram_mfma_min<<<g2, 256, 0, stream>>>(embr, scl, mask, neg);
    hinge_final<<<1, 1024, 0, stream>>>(neg, mask, out);
}

// Round 13
// 60.467 us; speedup vs baseline: 3.1258x; 1.0569x over previous
//
#include <hip/hip_runtime.h>
#include <hip/hip_bf16.h>

// Problem constants (fixed by the reference)
#define Bz 8
#define Cc 256
#define HWp 23104            // 152*152
#define Kk 1024
#define BK (Bz*Kk)
#define MARGIN_F 10.0f
#define BIGF 1e30f
#define TILE 128

typedef __attribute__((ext_vector_type(8))) short bf16x8;  // 8 bf16 = 4 VGPRs
typedef __attribute__((ext_vector_type(4))) float f32x4;   // MFMA 16x16 accumulator

__device__ __forceinline__ uint pk2(float a, float b) {
    return (uint)__hip_bfloat16_raw(__float2bfloat16(a)).x
         | ((uint)__hip_bfloat16_raw(__float2bfloat16(b)).x << 16);
}

// ---------------------------------------------------------------------------
// K0: per-batch bitonic sort of packed (hw<<10 | k).  hw < 2^15, k < 2^10 ->
// 25-bit keys, unique (k in low bits) -> deterministic total order.
// 1024 threads, 1 element each, 55 compare-exchange stages in LDS.
// Also does neg_min init (ws is poisoned once, never re-poisoned).
// Why sort: R12 line-math -- 1024 draws touch ~183 of 361 lines/plane =
// 24 MB true traffic (the 189MB stream reads 8x too much; R7's unsorted
// scatter had 24MB but random order = latency-bound).  Sorted order makes
// the gather a near-sequential line stream, each line fetched exactly once.
// ---------------------------------------------------------------------------
__global__ __launch_bounds__(1024) void sort_ind(
    const int* __restrict__ ind, uint* __restrict__ sorted,
    unsigned* __restrict__ neg)
{
    __shared__ uint a[Kk];
    const int b = blockIdx.x, tid = threadIdx.x;
    a[tid] = ((uint)ind[b * Kk + tid] << 10) | (uint)tid;
    neg[b * Kk + tid] = __float_as_uint(BIGF);
    __syncthreads();
    for (int size = 2; size <= Kk; size <<= 1) {
        for (int stride = size >> 1; stride > 0; stride >>= 1) {
            if ((tid & stride) == 0) {
                int j = tid | stride;
                uint xv = a[tid], yv = a[j];
                bool up = ((tid & size) == 0);
                if ((xv > yv) == up) { a[tid] = yv; a[j] = xv; }
            }
            __syncthreads();
        }
    }
    sorted[b * Kk + tid] = a[tid];
}

// ---------------------------------------------------------------------------
// K1: sorted gather.  Block = (kq, 32-channel group, batch) = 16x8x8 = 1024.
// Thread t: sorted entry kl = t>>2 (64 per block), channel octet cq = t&3.
// 8 independent scalar loads/thread from 8 planes; consecutive lanes read
// ascending hw -> hardware-coalesced near-sequential line fetches; sorted
// kq-ranges are position-disjoint -> each line fetched once, ~24 MB total.
// Writes: lanes (kl, cq=0..3) produce 4x16B = ONE full 64B embr line per k,
// written exactly once.  embr content bitwise-identical to R7/R11.
// ---------------------------------------------------------------------------
__global__ __launch_bounds__(256) void sorted_gather(
    const float* __restrict__ x, const uint* __restrict__ sorted,
    __hip_bfloat16* __restrict__ embr)
{
    const int kq = blockIdx.x, cg = blockIdx.y, b = blockIdx.z;
    const int c0 = cg * 32;
    const int t = threadIdx.x;
    const int kl = t >> 2, cq = t & 3;
    uint e = sorted[b * Kk + kq * 64 + kl];
    int hw = (int)(e >> 10), k = (int)(e & 1023u);
    const float* xp = x + (size_t)(b * Cc + c0 + cq * 8) * HWp + hw;
    float v[8];
    #pragma unroll
    for (int j = 0; j < 8; ++j) v[j] = xp[(size_t)j * HWp];
    uint4 o = make_uint4(pk2(v[0], v[1]), pk2(v[2], v[3]),
                         pk2(v[4], v[5]), pk2(v[6], v[7]));
    *(uint4*)((ushort*)embr + (size_t)(b * Kk + k) * Cc + c0 + cq * 8) = o;
}

// ---------------------------------------------------------------------------
// K2: rownorm — one wave per row (verbatim R6/R11, proven).
// scl = 10/max(sqrt(ssq),eps) over the ROUNDED bf16 row (duplicate rows stay
// bitwise-identical -> d2_dup ~ 0, the loss signal).
// ---------------------------------------------------------------------------
__global__ __launch_bounds__(256) void rownorm(
    const __hip_bfloat16* __restrict__ embr, float* __restrict__ scl)
{
    int row  = blockIdx.x * 4 + (threadIdx.x >> 6);
    int lane = threadIdx.x & 63;
    uint2 v = *((const uint2*)((const ushort*)embr + (size_t)row * Cc) + lane);
    float f0 = __uint_as_float(v.x << 16);
    float f1 = __uint_as_float(v.x & 0xffff0000u);
    float f2 = __uint_as_float(v.y << 16);
    float f3 = __uint_as_float(v.y & 0xffff0000u);
    float s = f0*f0 + f1*f1 + f2*f2 + f3*f3;
    #pragma unroll
    for (int off = 32; off; off >>= 1) s += __shfl_xor(s, off);
    if (lane == 0)
        scl[row] = 10.0f / fmaxf(sqrtf(s), 1e-12f);
}

// ---------------------------------------------------------------------------
// K3: Gram via bf16 MFMA with LDS-staged panels (verbatim R5/R11, proven) +
// fused masked-min.  d2 = 200 - 2*scl_i*scl_j*Graw (||emb||^2 == 100 by
// construction), clamped >= 0 BEFORE the uint-bit atomicMin.
// ---------------------------------------------------------------------------
__global__ __launch_bounds__(256) void gram_mfma_min(
    const __hip_bfloat16* __restrict__ emb, const float* __restrict__ scl,
    const int* __restrict__ mask, unsigned* __restrict__ neg)
{
    __shared__ __align__(16) short As[TILE * 64];   // 16 KB
    __shared__ __align__(16) short Bs[TILE * 64];   // 16 KB
    int b  = blockIdx.z;
    int i0 = blockIdx.y * TILE;
    int j0 = blockIdx.x * TILE;
    int w  = threadIdx.x >> 6, l = threadIdx.x & 63;
    int wr = w >> 1, wc = w & 1;          // wave's 64x64 quadrant
    int lr = l & 15, lg = l >> 4;         // lane row / k-group

    const short* E  = (const short*)emb + (size_t)b * Kk * Cc;
    const short* EA = E + (size_t)i0 * Cc;
    const short* EB = E + (size_t)j0 * Cc;

    // staging: instr t (=w*4+q) fills LDS rows t*8..t*8+7; lane l ->
    // row offset l/8, slot l%8; source k-chunk = (l%8) ^ (l/8).
    const int lrow = l >> 3;
    const int lsub = (l & 7) ^ lrow;

    f32x4 acc[4][4] = {};
    for (int k0 = 0; k0 < Cc; k0 += 64) {
        #pragma unroll
        for (int q = 0; q < 4; ++q) {
            int t = w * 4 + q;
            int r = t * 8 + lrow;
            __builtin_amdgcn_global_load_lds(
                (const __attribute__((address_space(1))) void*)(EA + (size_t)r * Cc + k0 + lsub * 8),
                (__attribute__((address_space(3))) void*)&As[t * 512], 16, 0, 0);
            __builtin_amdgcn_global_load_lds(
                (const __attribute__((address_space(1))) void*)(EB + (size_t)r * Cc + k0 + lsub * 8),
                (__attribute__((address_space(3))) void*)&Bs[t * 512], 16, 0, 0);
        }
        __syncthreads();

        #pragma unroll
        for (int kk = 0; kk < 2; ++kk) {
            bf16x8 af[4], bf[4];
            #pragma unroll
            for (int f = 0; f < 4; ++f) {
                int ra = wr * 64 + f * 16 + lr;
                af[f] = *(const bf16x8*)&As[ra * 64 + (((kk * 4 + lg) ^ (ra & 7)) << 3)];
                int rb = wc * 64 + f * 16 + lr;
                bf[f] = *(const bf16x8*)&Bs[rb * 64 + (((kk * 4 + lg) ^ (rb & 7)) << 3)];
            }
            #pragma unroll
            for (int fi = 0; fi < 4; ++fi)
                #pragma unroll
                for (int fj = 0; fj < 4; ++fj)
                    acc[fi][fj] = __builtin_amdgcn_mfma_f32_16x16x32_bf16(
                                      af[fi], bf[fj], acc[fi][fj], 0, 0, 0);
        }
        __syncthreads();
    }

    const int* mb = mask + b * Kk;
    float cjv[4]; int jgv[4]; bool jva[4];
    #pragma unroll
    for (int fj = 0; fj < 4; ++fj) {
        int jg = j0 + wc*64 + fj*16 + lr;
        jgv[fj] = jg;
        cjv[fj] = scl[b * Kk + jg];
        jva[fj] = (mb[jg] != 0);
    }
    #pragma unroll
    for (int fi = 0; fi < 4; ++fi) {
        #pragma unroll
        for (int r = 0; r < 4; ++r) {
            int ig = i0 + wr*64 + fi*16 + 4*lg + r;
            float ci = scl[b * Kk + ig];
            float m = BIGF;
            #pragma unroll
            for (int fj = 0; fj < 4; ++fj) {
                float d2 = fmaxf(200.0f - 2.0f * ci * cjv[fj] * acc[fi][fj][r], 0.0f);
                bool ok = jva[fj] && (jgv[fj] != ig);
                m = ok ? fminf(m, d2) : m;
            }
            #pragma unroll
            for (int off = 1; off < 16; off <<= 1)
                m = fminf(m, __shfl_xor(m, off));
            if (lr == 0)
                atomicMin(&neg[b * Kk + ig], __float_as_uint(m));
        }
    }
}

// ---------------------------------------------------------------------------
// K4: hinge + mean (verbatim R6/R11, proven).
// ---------------------------------------------------------------------------
__global__ __launch_bounds__(1024) void hinge_final(
    const unsigned* __restrict__ neg, const int* __restrict__ mask,
    float* __restrict__ out)
{
    float h = 0.f, v = 0.f;
    for (int i = threadIdx.x; i < BK; i += 1024) {
        if (mask[i] != 0) {
            float d = sqrtf(__uint_as_float(neg[i]));
            h += fmaxf(MARGIN_F - d, 0.f);
            v += 1.f;
        }
    }
    #pragma unroll
    for (int off = 32; off; off >>= 1) {
        h += __shfl_xor(h, off);
        v += __shfl_xor(v, off);
    }
    __shared__ float sh[16], sv[16];
    int w = threadIdx.x >> 6;
    if ((threadIdx.x & 63) == 0) { sh[w] = h; sv[w] = v; }
    __syncthreads();
    if (threadIdx.x == 0) {
        float H = 0.f, V = 0.f;
        #pragma unroll
        for (int i = 0; i < 16; ++i) { H += sh[i]; V += sv[i]; }
        out[0] = H / V;
    }
}

// ---------------------------------------------------------------------------
extern "C" void kernel_launch(void* const* d_in, const int* in_sizes, int n_in,
                              void* d_out, int out_size, void* d_ws, size_t ws_size,
                              hipStream_t stream) {
    const float* x    = (const float*)d_in[0];   // [B,C,H,W] fp32
    const int*   ind  = (const int*)d_in[1];     // [B,K] int32
    const int*   mask = (const int*)d_in[2];     // [B,K] int32
    float* out = (float*)d_out;

    // ws layout: embr bf16 [B*K][C] (4 MB) | scl f32 [B*K] | neg u32 [B*K]
    //            | sorted u32 [B*K]
    __hip_bfloat16* embr = (__hip_bfloat16*)d_ws;
    float*    scl    = (float*)((char*)d_ws + (size_t)BK * Cc * sizeof(__hip_bfloat16));
    unsigned* neg    = (unsigned*)(scl + BK);
    uint*     sorted = (uint*)(neg + BK);

    sort_ind<<<Bz, 1024, 0, stream>>>(ind, sorted, neg);
    dim3 g1(16, Cc / 32, Bz);                 // (16 kq, 8 cgroups, 8 b)
    sorted_gather<<<g1, 256, 0, stream>>>(x, sorted, embr);
    rownorm<<<BK / 4, 256, 0, stream>>>(embr, scl);
    dim3 g2(Kk / TILE, Kk / TILE, Bz);
    gram_mfma_min<<<g2, 256, 0, stream>>>(embr, scl, mask, neg);
    hinge_final<<<1, 1024, 0, stream>>>(neg, mask, out);
}

// Round 14
// 57.904 us; speedup vs baseline: 3.2641x; 1.0442x over previous
//
#include <hip/hip_runtime.h>
#include <hip/hip_bf16.h>

// Problem constants (fixed by the reference)
#define Bz 8
#define Cc 256
#define HWp 23104            // 152*152
#define Kk 1024
#define BK (Bz*Kk)
#define MARGIN_F 10.0f
#define BIGF 1e30f
#define TILE 128
#define NBK 128              // buckets (hw>>8 in [0,90], padded to 128)

typedef __attribute__((ext_vector_type(8))) short bf16x8;  // 8 bf16 = 4 VGPRs
typedef __attribute__((ext_vector_type(4))) float f32x4;   // MFMA 16x16 accumulator

__device__ __forceinline__ uint pk2(float a, float b) {
    return (uint)__hip_bfloat16_raw(__float2bfloat16(a)).x
         | ((uint)__hip_bfloat16_raw(__float2bfloat16(b)).x << 16);
}

// ---------------------------------------------------------------------------
// K0: per-batch BUCKET sort (replaces R12's bitonic).  R12 lesson: bitonic =
// 55 barrier-serial stages on 8 blocks (248 CUs idle) ~ 12-22us, eating the
// sorted-gather win.  The gather only needs LOCALITY, not total order:
// bucket = hw>>8 (256 positions = 16 lines per bucket).  3 barriers total:
// LDS histogram atomics -> serial 128-prefix (thread 0, ~0.5us) -> scatter
// via LDS cursor atomicAdd.  Intra-bucket order is timing-dependent, but
// every OUTPUT byte is order-independent: each k writes its own embr row
// (value = f(k, ind[k]) only), neg is atomicMin.  Also does neg_min init.
// ---------------------------------------------------------------------------
__global__ __launch_bounds__(1024) void bucket_sort(
    const int* __restrict__ ind, uint* __restrict__ sorted,
    unsigned* __restrict__ neg)
{
    __shared__ uint cur[NBK];
    const int b = blockIdx.x, tid = threadIdx.x;
    if (tid < NBK) cur[tid] = 0;
    neg[b * Kk + tid] = __float_as_uint(BIGF);
    __syncthreads();
    int hw = ind[b * Kk + tid];
    int bk = hw >> 8;                       // 0..90
    atomicAdd(&cur[bk], 1u);
    __syncthreads();
    if (tid == 0) {                         // exclusive prefix (serial, 128)
        uint acc = 0;
        #pragma unroll
        for (int i = 0; i < NBK; ++i) { uint c = cur[i]; cur[i] = acc; acc += c; }
    }
    __syncthreads();
    uint slot = atomicAdd(&cur[bk], 1u);    // unique slot within bucket
    sorted[b * Kk + slot] = ((uint)hw << 10) | (uint)tid;
}

// ---------------------------------------------------------------------------
// K1: sorted gather (verbatim R12, proven).  Block = (kq, 32-ch group, b).
// Thread t: sorted entry kl = t>>2, channel octet cq = t&3; 8 independent
// loads/thread; bucket-local hw ordering -> near-sequential line fetches,
// each line fetched ~once (~24 MB total).  Lanes (kl, cq=0..3) write ONE
// full 64B embr line per k, exactly once (bitwise-identical to R7/R11/R12).
// ---------------------------------------------------------------------------
__global__ __launch_bounds__(256) void sorted_gather(
    const float* __restrict__ x, const uint* __restrict__ sorted,
    __hip_bfloat16* __restrict__ embr)
{
    const int kq = blockIdx.x, cg = blockIdx.y, b = blockIdx.z;
    const int c0 = cg * 32;
    const int t = threadIdx.x;
    const int kl = t >> 2, cq = t & 3;
    uint e = sorted[b * Kk + kq * 64 + kl];
    int hw = (int)(e >> 10), k = (int)(e & 1023u);
    const float* xp = x + (size_t)(b * Cc + c0 + cq * 8) * HWp + hw;
    float v[8];
    #pragma unroll
    for (int j = 0; j < 8; ++j) v[j] = xp[(size_t)j * HWp];
    uint4 o = make_uint4(pk2(v[0], v[1]), pk2(v[2], v[3]),
                         pk2(v[4], v[5]), pk2(v[6], v[7]));
    *(uint4*)((ushort*)embr + (size_t)(b * Kk + k) * Cc + c0 + cq * 8) = o;
}

// ---------------------------------------------------------------------------
// K2: rownorm — one wave per row (verbatim R6/R11, proven).
// ---------------------------------------------------------------------------
__global__ __launch_bounds__(256) void rownorm(
    const __hip_bfloat16* __restrict__ embr, float* __restrict__ scl)
{
    int row  = blockIdx.x * 4 + (threadIdx.x >> 6);
    int lane = threadIdx.x & 63;
    uint2 v = *((const uint2*)((const ushort*)embr + (size_t)row * Cc) + lane);
    float f0 = __uint_as_float(v.x << 16);
    float f1 = __uint_as_float(v.x & 0xffff0000u);
    float f2 = __uint_as_float(v.y << 16);
    float f3 = __uint_as_float(v.y & 0xffff0000u);
    float s = f0*f0 + f1*f1 + f2*f2 + f3*f3;
    #pragma unroll
    for (int off = 32; off; off >>= 1) s += __shfl_xor(s, off);
    if (lane == 0)
        scl[row] = 10.0f / fmaxf(sqrtf(s), 1e-12f);
}

// ---------------------------------------------------------------------------
// K3: Gram via bf16 MFMA with LDS-staged panels (verbatim R5/R11, proven) +
// fused masked-min.  d2 = 200 - 2*scl_i*scl_j*Graw, clamped >= 0 BEFORE the
// uint-bit atomicMin (duplicate-index pairs = the loss signal).
// ---------------------------------------------------------------------------
__global__ __launch_bounds__(256) void gram_mfma_min(
    const __hip_bfloat16* __restrict__ emb, const float* __restrict__ scl,
    const int* __restrict__ mask, unsigned* __restrict__ neg)
{
    __shared__ __align__(16) short As[TILE * 64];   // 16 KB
    __shared__ __align__(16) short Bs[TILE * 64];   // 16 KB
    int b  = blockIdx.z;
    int i0 = blockIdx.y * TILE;
    int j0 = blockIdx.x * TILE;
    int w  = threadIdx.x >> 6, l = threadIdx.x & 63;
    int wr = w >> 1, wc = w & 1;          // wave's 64x64 quadrant
    int lr = l & 15, lg = l >> 4;         // lane row / k-group

    const short* E  = (const short*)emb + (size_t)b * Kk * Cc;
    const short* EA = E + (size_t)i0 * Cc;
    const short* EB = E + (size_t)j0 * Cc;

    // staging: instr t (=w*4+q) fills LDS rows t*8..t*8+7; lane l ->
    // row offset l/8, slot l%8; source k-chunk = (l%8) ^ (l/8).
    const int lrow = l >> 3;
    const int lsub = (l & 7) ^ lrow;

    f32x4 acc[4][4] = {};
    for (int k0 = 0; k0 < Cc; k0 += 64) {
        #pragma unroll
        for (int q = 0; q < 4; ++q) {
            int t = w * 4 + q;
            int r = t * 8 + lrow;
            __builtin_amdgcn_global_load_lds(
                (const __attribute__((address_space(1))) void*)(EA + (size_t)r * Cc + k0 + lsub * 8),
                (__attribute__((address_space(3))) void*)&As[t * 512], 16, 0, 0);
            __builtin_amdgcn_global_load_lds(
                (const __attribute__((address_space(1))) void*)(EB + (size_t)r * Cc + k0 + lsub * 8),
                (__attribute__((address_space(3))) void*)&Bs[t * 512], 16, 0, 0);
        }
        __syncthreads();

        #pragma unroll
        for (int kk = 0; kk < 2; ++kk) {
            bf16x8 af[4], bf[4];
            #pragma unroll
            for (int f = 0; f < 4; ++f) {
                int ra = wr * 64 + f * 16 + lr;
                af[f] = *(const bf16x8*)&As[ra * 64 + (((kk * 4 + lg) ^ (ra & 7)) << 3)];
                int rb = wc * 64 + f * 16 + lr;
                bf[f] = *(const bf16x8*)&Bs[rb * 64 + (((kk * 4 + lg) ^ (rb & 7)) << 3)];
            }
            #pragma unroll
            for (int fi = 0; fi < 4; ++fi)
                #pragma unroll
                for (int fj = 0; fj < 4; ++fj)
                    acc[fi][fj] = __builtin_amdgcn_mfma_f32_16x16x32_bf16(
                                      af[fi], bf[fj], acc[fi][fj], 0, 0, 0);
        }
        __syncthreads();
    }

    const int* mb = mask + b * Kk;
    float cjv[4]; int jgv[4]; bool jva[4];
    #pragma unroll
    for (int fj = 0; fj < 4; ++fj) {
        int jg = j0 + wc*64 + fj*16 + lr;
        jgv[fj] = jg;
        cjv[fj] = scl[b * Kk + jg];
        jva[fj] = (mb[jg] != 0);
    }
    #pragma unroll
    for (int fi = 0; fi < 4; ++fi) {
        #pragma unroll
        for (int r = 0; r < 4; ++r) {
            int ig = i0 + wr*64 + fi*16 + 4*lg + r;
            float ci = scl[b * Kk + ig];
            float m = BIGF;
            #pragma unroll
            for (int fj = 0; fj < 4; ++fj) {
                float d2 = fmaxf(200.0f - 2.0f * ci * cjv[fj] * acc[fi][fj][r], 0.0f);
                bool ok = jva[fj] && (jgv[fj] != ig);
                m = ok ? fminf(m, d2) : m;
            }
            #pragma unroll
            for (int off = 1; off < 16; off <<= 1)
                m = fminf(m, __shfl_xor(m, off));
            if (lr == 0)
                atomicMin(&neg[b * Kk + ig], __float_as_uint(m));
        }
    }
}

// ---------------------------------------------------------------------------
// K4: hinge + mean (verbatim R6/R11, proven).
// ---------------------------------------------------------------------------
__global__ __launch_bounds__(1024) void hinge_final(
    const unsigned* __restrict__ neg, const int* __restrict__ mask,
    float* __restrict__ out)
{
    float h = 0.f, v = 0.f;
    for (int i = threadIdx.x; i < BK; i += 1024) {
        if (mask[i] != 0) {
            float d = sqrtf(__uint_as_float(neg[i]));
            h += fmaxf(MARGIN_F - d, 0.f);
            v += 1.f;
        }
    }
    #pragma unroll
    for (int off = 32; off; off >>= 1) {
        h += __shfl_xor(h, off);
        v += __shfl_xor(v, off);
    }
    __shared__ float sh[16], sv[16];
    int w = threadIdx.x >> 6;
    if ((threadIdx.x & 63) == 0) { sh[w] = h; sv[w] = v; }
    __syncthreads();
    if (threadIdx.x == 0) {
        float H = 0.f, V = 0.f;
        #pragma unroll
        for (int i = 0; i < 16; ++i) { H += sh[i]; V += sv[i]; }
        out[0] = H / V;
    }
}

// ---------------------------------------------------------------------------
extern "C" void kernel_launch(void* const* d_in, const int* in_sizes, int n_in,
                              void* d_out, int out_size, void* d_ws, size_t ws_size,
                              hipStream_t stream) {
    const float* x    = (const float*)d_in[0];   // [B,C,H,W] fp32
    const int*   ind  = (const int*)d_in[1];     // [B,K] int32
    const int*   mask = (const int*)d_in[2];     // [B,K] int32
    float* out = (float*)d_out;

    // ws layout: embr bf16 [B*K][C] (4 MB) | scl f32 [B*K] | neg u32 [B*K]
    //            | sorted u32 [B*K]
    __hip_bfloat16* embr = (__hip_bfloat16*)d_ws;
    float*    scl    = (float*)((char*)d_ws + (size_t)BK * Cc * sizeof(__hip_bfloat16));
    unsigned* neg    = (unsigned*)(scl + BK);
    uint*     sorted = (uint*)(neg + BK);

    bucket_sort<<<Bz, 1024, 0, stream>>>(ind, sorted, neg);
    dim3 g1(16, Cc / 32, Bz);                 // (16 kq, 8 cgroups, 8 b)
    sorted_gather<<<g1, 256, 0, stream>>>(x, sorted, embr);
    rownorm<<<BK / 4, 256, 0, stream>>>(embr, scl);
    dim3 g2(Kk / TILE, Kk / TILE, Bz);
    gram_mfma_min<<<g2, 256, 0, stream>>>(embr, scl, mask, neg);
    hinge_final<<<1, 1024, 0, stream>>>(neg, mask, out);
}